// Round 4
// baseline (471.310 us; speedup 1.0000x reference)
//
#include <hip/hip_runtime.h>
#include <math.h>
#include <float.h>

// Problem dims (fixed by setup_inputs)
#define BB 32
#define TT 2048
#define OO 128
#define CC 80
#define EPSF 1e-7f
#define NT 256
#define SLOTS (TT / NT)   // 8 columns per thread
#define CPAD 84           // padded LDS class-row stride (floats, mult of 4)

// ---------------------------------------------------------------------------
// Fused cost kernel: block = (t-tile of 256, b). Class tile staged in LDS
// (no dynamic-indexed register array -> no scratch spill). Log-softmax in the
// exact sequential op order of the reference -> bit-identical fp32 cost.
// cost layout: [B][O][T].
// ---------------------------------------------------------------------------
__global__ __launch_bounds__(NT) void cost_fused_kernel(
    const float* __restrict__ pb, const float* __restrict__ tb,
    const float* __restrict__ cls, const int* __restrict__ tcls,
    float* __restrict__ cost) {
#pragma clang fp contract(off)
    int b = blockIdx.y;
    int t0 = blockIdx.x * NT;
    int tid = threadIdx.x;

    __shared__ float s_xv[NT * CPAD];   // 256 tokens x 80 classes (pad 84)
    __shared__ float s_x1[OO], s_y1[OO], s_x2[OO], s_y2[OO], s_w2h2[OO];
    __shared__ int s_tc[OO];

    // stage class tile: coalesced float4 global reads, aligned LDS writes
    const float* cbase = cls + ((size_t)b * TT + t0) * CC;
    #pragma unroll
    for (int k = 0; k < (NT * CC) / (NT * 4); ++k) {   // 20 iters
        int idx4 = (k * NT + tid) * 4;
        float4 vv = *(const float4*)(cbase + idx4);
        int r = idx4 / CC;
        int c = idx4 - r * CC;
        *(float4*)(&s_xv[r * CPAD + c]) = vv;
    }
    if (tid < OO) {
        float4 tbox = ((const float4*)tb)[b * OO + tid];
        float x1 = tbox.x - tbox.z / 2.f;
        float y1 = tbox.y - tbox.w / 2.f;
        float x2 = tbox.x + tbox.z / 2.f;
        float y2 = tbox.y + tbox.w / 2.f;
        s_x1[tid] = x1; s_y1[tid] = y1; s_x2[tid] = x2; s_y2[tid] = y2;
        float w2 = x2 - x1;
        float h2 = (y2 - y1) + EPSF;
        s_w2h2[tid] = w2 * h2;
        s_tc[tid] = tcls[b * OO + tid];
    }
    __syncthreads();

    size_t bt = (size_t)b * TT + t0 + tid;
    float4 pbox = ((const float4*)pb)[bt];
    float b1x1 = pbox.x - pbox.z / 2.f;
    float b1y1 = pbox.y - pbox.w / 2.f;
    float b1x2 = pbox.x + pbox.z / 2.f;
    float b1y2 = pbox.y + pbox.w / 2.f;
    float w1 = b1x2 - b1x1;
    float h1 = (b1y2 - b1y1) + EPSF;
    float w1h1 = w1 * h1;

    // log-softmax normalizers, strictly sequential in c (bit-identical)
    const float* xr = &s_xv[tid * CPAD];
    float m = xr[0];
    #pragma unroll
    for (int c = 1; c < CC; ++c) m = fmaxf(m, xr[c]);
    float ssum = 0.f;
    #pragma unroll
    for (int c = 0; c < CC; ++c) ssum += expf(xr[c] - m);
    float ls = logf(ssum);

    float* cbt = cost + (size_t)b * OO * TT + t0;
    for (int o = 0; o < OO; ++o) {
        float b2x1 = s_x1[o], b2y1 = s_y1[o], b2x2 = s_x2[o], b2y2 = s_y2[o];
        float iw = fminf(b1x2, b2x2) - fmaxf(b1x1, b2x1);
        float ih = fminf(b1y2, b2y2) - fmaxf(b1y1, b2y1);
        iw = fmaxf(iw, 0.f);
        ih = fmaxf(ih, 0.f);
        float inter = iw * ih;
        float uni = ((w1h1 + s_w2h2[o]) - inter) + EPSF;
        float iou = inter / uni;
        float cw = fmaxf(b1x2, b2x2) - fminf(b1x1, b2x1);
        float ch = fmaxf(b1y2, b2y2) - fminf(b1y1, b2y1);
        float c_area = (cw * ch) + EPSF;
        float giou = iou - (c_area - uni) / c_area;
        float bbox_loss = 1.0f - giou;

        float xc = xr[s_tc[o]];
        float shifted = xc - m;
        float cls_neg = -(shifted - ls);

        cbt[(size_t)o * TT + tid] = bbox_loss + cls_neg;
    }
}

// ---------------------------------------------------------------------------
// Jonker-Volgenant LSA, one block per batch. v[]/shortest[] register-resident
// (8 cols/thread); SC is a per-lane bitmask; path[] stored LDS-swizzled
// [s*NT+tid] (lane-stride 4B -> conflict-free). The block's 1 MB cost slice
// is streamed through L2 once at start (4 blocks/XCD x 1 MB = 4 MB L2) so the
// serial per-step row loads hit L2 instead of HBM. One __syncthreads per
// shortest-path step. All fp64 expression orders identical to numpy ref.
// ---------------------------------------------------------------------------
__global__ __launch_bounds__(NT) void lsa_kernel(const float* __restrict__ cost,
                                                 float* __restrict__ dummy,
                                                 int* __restrict__ out) {
#pragma clang fp contract(off)
    int b = blockIdx.x;
    int tid = threadIdx.x;
    int lane = tid & 63;
    int wave = tid >> 6;

    __shared__ int sh_path[TT];        // swizzled: col j at [(j&7)*NT + (j>>3)]
    __shared__ int sh_row4col[TT];
    __shared__ double sh_u[OO];
    __shared__ int sh_col4row[OO];
    __shared__ double sh_selm[OO + 8]; // shortest value at each selection
    __shared__ int sh_selrow[OO + 8];  // row entered from each selected col
    __shared__ double cand_val[2][4];
    __shared__ int cand_idx[2][4];

    const float* cb = cost + (size_t)b * OO * TT;

    // ---- L2 warm: stream the whole 1 MB slice, sink-sum to defeat DCE ----
    {
        const float4* cb4 = (const float4*)cb;
        float sx = 0.f, sy = 0.f, sz = 0.f, sw = 0.f;
        for (int k = 0; k < (OO * TT) / (4 * NT); ++k) {   // 256 iters
            float4 v = cb4[k * NT + tid];
            sx += v.x; sy += v.y; sz += v.z; sw += v.w;
        }
        dummy[b * NT + tid] = (sx + sy) + (sz + sw);
    }

    double v_[SLOTS];
    double key[SLOTS];
    #pragma unroll
    for (int s = 0; s < SLOTS; ++s) v_[s] = 0.0;

    for (int j = tid; j < TT; j += NT) sh_row4col[j] = -1;
    if (tid < OO) { sh_u[tid] = 0.0; sh_col4row[tid] = -1; }
    __syncthreads();

    const int jbase = tid * SLOTS;

    for (int cur = 0; cur < OO; ++cur) {
        #pragma unroll
        for (int s = 0; s < SLOTS; ++s) key[s] = INFINITY;
        int selbits = 0;
        double mv = 0.0;
        int i = cur;
        double ui = sh_u[cur];
        int L = 0, parity = 0, sink = -1;

        while (true) {
            const float* crow = cb + (size_t)i * TT + jbase;
            float4 c0 = *(const float4*)crow;
            float4 c1 = *(const float4*)(crow + 4);
            float cv[SLOTS] = {c0.x, c0.y, c0.z, c0.w, c1.x, c1.y, c1.z, c1.w};

            double bv = INFINITY;
            int bj = TT;
            #pragma unroll
            for (int s = 0; s < SLOTS; ++s) {
                if (!((selbits >> s) & 1)) {
                    // numpy order: r = min_val + c[i] - u[i] - v
                    double r = ((mv + (double)cv[s]) - ui) - v_[s];
                    if (r < key[s]) { key[s] = r; sh_path[s * NT + tid] = i; }
                    double kk = key[s];
                    if (kk < bv) { bv = kk; bj = jbase + s; }  // s asc = j asc
                }
            }
            // wave butterfly lexmin (val, idx) — all lanes end with wave min
            #pragma unroll
            for (int off = 1; off < 64; off <<= 1) {
                double ov = __shfl_xor(bv, off);
                int oj = __shfl_xor(bj, off);
                if (ov < bv || (ov == bv && oj < bj)) { bv = ov; bj = oj; }
            }
            if (lane == 0) { cand_val[parity][wave] = bv; cand_idx[parity][wave] = bj; }
            __syncthreads();

            // every thread combines the 4 wave candidates (broadcast reads)
            double MV = cand_val[parity][0];
            int BJ = cand_idx[parity][0];
            #pragma unroll
            for (int w = 1; w < 4; ++w) {
                double ov = cand_val[parity][w];
                int oj = cand_idx[parity][w];
                if (ov < MV || (ov == MV && oj < BJ)) { MV = ov; BJ = oj; }
            }
            mv = MV;
            if ((BJ >> 3) == tid) selbits |= 1 << (BJ & 7);  // mark SC (owner)

            int r4 = sh_row4col[BJ];   // broadcast LDS read
            if (r4 < 0) { sink = BJ; break; }
            if (tid == 0) { sh_selm[L] = MV; sh_selrow[L] = r4; }
            i = r4;
            ui = sh_u[i];
            L++;
            parity ^= 1;
        }

        double M = mv;
        // v[SC] -= M - shortest[SC]  (register-resident, per owner lane)
        #pragma unroll
        for (int s = 0; s < SLOTS; ++s)
            if ((selbits >> s) & 1) v_[s] = v_[s] - (M - key[s]);
        // u[visited rows] += M - shortest[their col]  (distinct rows)
        for (int k = tid; k < L; k += NT)
            sh_u[sh_selrow[k]] = sh_u[sh_selrow[k]] + (M - sh_selm[k]);
        if (tid == 0) {
            sh_u[cur] = sh_u[cur] + M;
            // augment along predecessor path (SC cols only -> path[] frozen)
            int j = sink;
            while (true) {
                int ii = sh_path[(j & 7) * NT + (j >> 3)];
                sh_row4col[j] = ii;
                int tmp = sh_col4row[ii];
                sh_col4row[ii] = j;
                j = tmp;
                if (ii == cur) break;
            }
        }
        __syncthreads();   // orders augment/u-writes vs next path
    }

    // order = argsort(col4row); pred_idx = col4row[order]; tgt_idx = order
    if (tid < OO) {
        int my = sh_col4row[tid];
        int rank = 0;
        for (int o = 0; o < OO; ++o) rank += (sh_col4row[o] < my) ? 1 : 0;
        out[(size_t)b * OO + rank] = my;         // pred_idx
        out[(size_t)(BB + b) * OO + rank] = tid; // tgt_idx
    }
}

// ---------------------------------------------------------------------------
extern "C" void kernel_launch(void* const* d_in, const int* in_sizes, int n_in,
                              void* d_out, int out_size, void* d_ws, size_t ws_size,
                              hipStream_t stream) {
    const float* pred_bboxes = (const float*)d_in[0];    // [B,T,4]
    const float* target_bboxes = (const float*)d_in[1];  // [B,O,4]
    const float* pred_classes = (const float*)d_in[2];   // [B,T,C]
    const int* target_classes = (const int*)d_in[3];     // [B,O]
    int* out = (int*)d_out;                              // [2,B,O] int32

    float* cost = (float*)d_ws;                   // [B][O][T] fp32 (32 MB)
    float* dummy = cost + (size_t)BB * OO * TT;   // 32 KB sink (defeats DCE)

    dim3 cgrid(TT / NT, BB);
    cost_fused_kernel<<<cgrid, NT, 0, stream>>>(pred_bboxes, target_bboxes,
                                                pred_classes, target_classes,
                                                cost);
    lsa_kernel<<<BB, NT, 0, stream>>>(cost, dummy, out);
}

// Round 5
// 393.143 us; speedup vs baseline: 1.1988x; 1.1988x over previous
//
#include <hip/hip_runtime.h>
#include <math.h>
#include <float.h>

// Problem dims (fixed by setup_inputs)
#define BB 32
#define TT 2048
#define OO 128
#define CC 80
#define EPSF 1e-7f
#define NT 256
#define SLOTS 8           // columns per thread
#define CPAD 84           // padded LDS class-row stride (floats)

struct alignas(16) URow { double u; int row; int pad; };   // u[row4col[j]], row4col[j]
struct alignas(8)  P2   { int i; int j; };                 // path row, its column
struct alignas(16) Cand { double v; int j; int pad; };

// DPP lexicographic-min step: incoming lanes always aggregate strictly-lower
// column ranges, so (tv <= bv) == exact first-index tie-break. Identity for
// invalid lanes = {+inf, INT_MAX}.
template<int CTRL>
__device__ __forceinline__ void dpp_lexmin(double& bv, int& bj) {
    int lo = __double2loint(bv), hi = __double2hiint(bv);
    int tlo = __builtin_amdgcn_update_dpp(0, lo, CTRL, 0xF, 0xF, false);
    int thi = __builtin_amdgcn_update_dpp(0x7FF00000, hi, CTRL, 0xF, 0xF, false);
    int tj  = __builtin_amdgcn_update_dpp(0x7FFFFFFF, bj, CTRL, 0xF, 0xF, false);
    double tv = __hiloint2double(thi, tlo);
    if (tv <= bv) { bv = tv; bj = tj; }
}

// ---------------------------------------------------------------------------
// Fused cost kernel (unchanged from round 3/4 — bit-identical to reference).
// ---------------------------------------------------------------------------
__global__ __launch_bounds__(NT) void cost_fused_kernel(
    const float* __restrict__ pb, const float* __restrict__ tb,
    const float* __restrict__ cls, const int* __restrict__ tcls,
    float* __restrict__ cost) {
#pragma clang fp contract(off)
    int b = blockIdx.y;
    int t0 = blockIdx.x * NT;
    int tid = threadIdx.x;

    __shared__ float s_xv[NT * CPAD];
    __shared__ float s_x1[OO], s_y1[OO], s_x2[OO], s_y2[OO], s_w2h2[OO];
    __shared__ int s_tc[OO];

    const float* cbase = cls + ((size_t)b * TT + t0) * CC;
    #pragma unroll
    for (int k = 0; k < CC / 4; ++k) {   // 20 iters
        int idx4 = (k * NT + tid) * 4;
        float4 vv = *(const float4*)(cbase + idx4);
        int r = idx4 / CC;
        int c = idx4 - r * CC;
        *(float4*)(&s_xv[r * CPAD + c]) = vv;
    }
    if (tid < OO) {
        float4 tbox = ((const float4*)tb)[b * OO + tid];
        float x1 = tbox.x - tbox.z / 2.f;
        float y1 = tbox.y - tbox.w / 2.f;
        float x2 = tbox.x + tbox.z / 2.f;
        float y2 = tbox.y + tbox.w / 2.f;
        s_x1[tid] = x1; s_y1[tid] = y1; s_x2[tid] = x2; s_y2[tid] = y2;
        float w2 = x2 - x1;
        float h2 = (y2 - y1) + EPSF;
        s_w2h2[tid] = w2 * h2;
        s_tc[tid] = tcls[b * OO + tid];
    }
    __syncthreads();

    size_t bt = (size_t)b * TT + t0 + tid;
    float4 pbox = ((const float4*)pb)[bt];
    float b1x1 = pbox.x - pbox.z / 2.f;
    float b1y1 = pbox.y - pbox.w / 2.f;
    float b1x2 = pbox.x + pbox.z / 2.f;
    float b1y2 = pbox.y + pbox.w / 2.f;
    float w1 = b1x2 - b1x1;
    float h1 = (b1y2 - b1y1) + EPSF;
    float w1h1 = w1 * h1;

    const float* xr = &s_xv[tid * CPAD];
    float m = xr[0];
    #pragma unroll
    for (int c = 1; c < CC; ++c) m = fmaxf(m, xr[c]);
    float ssum = 0.f;
    #pragma unroll
    for (int c = 0; c < CC; ++c) ssum += expf(xr[c] - m);
    float ls = logf(ssum);

    float* cbt = cost + (size_t)b * OO * TT + t0;
    for (int o = 0; o < OO; ++o) {
        float b2x1 = s_x1[o], b2y1 = s_y1[o], b2x2 = s_x2[o], b2y2 = s_y2[o];
        float iw = fminf(b1x2, b2x2) - fmaxf(b1x1, b2x1);
        float ih = fminf(b1y2, b2y2) - fmaxf(b1y1, b2y1);
        iw = fmaxf(iw, 0.f);
        ih = fmaxf(ih, 0.f);
        float inter = iw * ih;
        float uni = ((w1h1 + s_w2h2[o]) - inter) + EPSF;
        float iou = inter / uni;
        float cw = fmaxf(b1x2, b2x2) - fminf(b1x1, b2x1);
        float ch = fmaxf(b1y2, b2y2) - fminf(b1y1, b2y1);
        float c_area = (cw * ch) + EPSF;
        float giou = iou - (c_area - uni) / c_area;
        float bbox_loss = 1.0f - giou;

        float xc = xr[s_tc[o]];
        float shifted = xc - m;
        float cls_neg = -(shifted - ls);

        cbt[(size_t)o * TT + tid] = bbox_loss + cls_neg;
    }
}

// ---------------------------------------------------------------------------
// Jonker-Volgenant LSA, one block per batch. Serial-chain-minimized:
// DPP wave reduction, merged {u,row} struct (1 LDS hop), path2 chase
// (1 read/hop), next-augmentation row prefetch. fp64 op order identical to
// numpy -> bit-exact assignment.
// ---------------------------------------------------------------------------
__global__ __launch_bounds__(NT) void lsa_kernel(const float* __restrict__ cost,
                                                 int* __restrict__ out) {
#pragma clang fp contract(off)
    int b = blockIdx.x;
    int tid = threadIdx.x;
    int lane = tid & 63;
    int wave = tid >> 6;

    __shared__ URow sh_urow[TT];        // {u[row4col[j]], row4col[j]}
    __shared__ P2   sh_path2[TT];       // swizzled: col j at [(j&7)*NT + (j>>3)]
    __shared__ int  sh_row4col[TT];
    __shared__ int  sh_col4row[OO];
    __shared__ double sh_u[OO];
    __shared__ int  sh_selj[OO + 8];    // all popped columns (incl. sink)
    __shared__ double sh_selm[OO + 8];  // shortest at pop (non-sink)
    __shared__ int  sh_selrow[OO + 8];  // row entered (non-sink)
    __shared__ Cand sh_cand[2][4];

    const float* cb = cost + (size_t)b * OO * TT;
    const int jbase = tid * SLOTS;

    double v_[SLOTS];
    double key[SLOTS];
    #pragma unroll
    for (int s = 0; s < SLOTS; ++s) v_[s] = 0.0;

    for (int j = tid; j < TT; j += NT) { sh_row4col[j] = -1; sh_urow[j].row = -1; }
    if (tid < OO) { sh_u[tid] = 0.0; sh_col4row[tid] = -1; }

    // prefetch row 0 (first Dijkstra root)
    float4 pf0 = *(const float4*)(cb + jbase);
    float4 pf1 = *(const float4*)(cb + jbase + 4);
    __syncthreads();

    int par = 0;
    int Lprev = -1;   // refresh count from previous augmentation

    for (int cur = 0; cur < OO; ++cur) {
        // refresh urow for previously-selected columns (post-augment state)
        if (cur > 0 && tid <= Lprev) {
            int j = sh_selj[tid];
            int r = sh_row4col[j];
            URow t; t.u = sh_u[r]; t.row = r; t.pad = 0;
            sh_urow[j] = t;
        }

        #pragma unroll
        for (int s = 0; s < SLOTS; ++s) key[s] = INFINITY;
        int selbits = 0;
        double mv = 0.0;
        int i = cur, jc = -1;
        double ui = sh_u[cur];
        float4 c0 = pf0, c1 = pf1;
        int L = 0, sink;

        while (true) {
            float cv[SLOTS] = {c0.x, c0.y, c0.z, c0.w, c1.x, c1.y, c1.z, c1.w};

            double bv = INFINITY;
            int bj = TT;
            #pragma unroll
            for (int s = 0; s < SLOTS; ++s) {
                if (!((selbits >> s) & 1)) {
                    // numpy order: r = min_val + c[i] - u[i] - v
                    double r = ((mv + (double)cv[s]) - ui) - v_[s];
                    if (r < key[s]) {
                        key[s] = r;
                        P2 p; p.i = i; p.j = jc;
                        sh_path2[s * NT + tid] = p;
                    }
                    double kk = key[s];
                    if (kk < bv) { bv = kk; bj = jbase + s; }
                }
            }
            // wave lexmin via DPP (result accumulates into lane 63)
            dpp_lexmin<0x111>(bv, bj);   // row_shr:1
            dpp_lexmin<0x112>(bv, bj);   // row_shr:2
            dpp_lexmin<0x114>(bv, bj);   // row_shr:4
            dpp_lexmin<0x118>(bv, bj);   // row_shr:8
            dpp_lexmin<0x142>(bv, bj);   // row_bcast:15
            dpp_lexmin<0x143>(bv, bj);   // row_bcast:31
            int rlo = __builtin_amdgcn_readlane(__double2loint(bv), 63);
            int rhi = __builtin_amdgcn_readlane(__double2hiint(bv), 63);
            double wv = __hiloint2double(rhi, rlo);
            int wj = __builtin_amdgcn_readlane(bj, 63);

            par ^= 1;
            if (lane == 0) {
                Cand c; c.v = wv; c.j = wj; c.pad = 0;
                sh_cand[par][wave] = c;
            }
            __syncthreads();

            // combine 4 wave candidates (broadcast reads, all threads)
            Cand cc = sh_cand[par][0];
            double MV = cc.v; int BJ = cc.j;
            #pragma unroll
            for (int w = 1; w < 4; ++w) {
                Cand c2 = sh_cand[par][w];
                if (c2.v < MV || (c2.v == MV && c2.j < BJ)) { MV = c2.v; BJ = c2.j; }
            }
            mv = MV;
            if ((BJ >> 3) == tid) selbits |= 1 << (BJ & 7);  // mark SC (owner)
            if (tid == 0) sh_selj[L] = BJ;

            URow ur = sh_urow[BJ];        // one broadcast 16B read
            if (ur.row < 0) { sink = BJ; break; }
            if (tid == 0) { sh_selm[L] = MV; sh_selrow[L] = ur.row; }
            i = ur.row; ui = ur.u; jc = BJ;
            L++;
            // load next row (serial-dependent)
            const float* crow = cb + (size_t)i * TT + jbase;
            c0 = *(const float4*)crow;
            c1 = *(const float4*)(crow + 4);
        }

        // prefetch next augmentation's root row (statically known)
        if (cur + 1 < OO) {
            const float* nrow = cb + (size_t)(cur + 1) * TT + jbase;
            pf0 = *(const float4*)nrow;
            pf1 = *(const float4*)(nrow + 4);
        }

        double M = mv;
        // v[SC] -= M - shortest[SC]  (register-resident per owner lane)
        #pragma unroll
        for (int s = 0; s < SLOTS; ++s)
            if ((selbits >> s) & 1) v_[s] = v_[s] - (M - key[s]);
        // u[visited rows] += M - shortest[their col]
        for (int k = tid; k < L; k += NT)
            sh_u[sh_selrow[k]] = sh_u[sh_selrow[k]] + (M - sh_selm[k]);
        if (tid == 0) {
            sh_u[cur] = sh_u[cur] + M;
            // augment: 1 LDS read per hop via path2 {row, row's old column}
            int j = sink;
            while (true) {
                P2 p = sh_path2[(j & 7) * NT + (j >> 3)];
                int ii = p.i;
                sh_row4col[j] = ii;
                sh_col4row[ii] = j;
                if (ii == cur) break;
                j = p.j;
            }
        }
        Lprev = L;   // selj has L+1 valid entries (0..L incl. sink)
        __syncthreads();
    }

    // order = argsort(col4row); pred_idx = col4row[order]; tgt_idx = order
    if (tid < OO) {
        int my = sh_col4row[tid];
        int rank = 0;
        for (int o = 0; o < OO; ++o) rank += (sh_col4row[o] < my) ? 1 : 0;
        out[(size_t)b * OO + rank] = my;         // pred_idx
        out[(size_t)(BB + b) * OO + rank] = tid; // tgt_idx
    }
}

// ---------------------------------------------------------------------------
extern "C" void kernel_launch(void* const* d_in, const int* in_sizes, int n_in,
                              void* d_out, int out_size, void* d_ws, size_t ws_size,
                              hipStream_t stream) {
    const float* pred_bboxes = (const float*)d_in[0];    // [B,T,4]
    const float* target_bboxes = (const float*)d_in[1];  // [B,O,4]
    const float* pred_classes = (const float*)d_in[2];   // [B,T,C]
    const int* target_classes = (const int*)d_in[3];     // [B,O]
    int* out = (int*)d_out;                              // [2,B,O] int32

    float* cost = (float*)d_ws;  // [B][O][T] fp32 (32 MB)

    dim3 cgrid(TT / NT, BB);
    cost_fused_kernel<<<cgrid, NT, 0, stream>>>(pred_bboxes, target_bboxes,
                                                pred_classes, target_classes,
                                                cost);
    lsa_kernel<<<BB, NT, 0, stream>>>(cost, out);
}

// Round 6
// 291.937 us; speedup vs baseline: 1.6144x; 1.3467x over previous
//
#include <hip/hip_runtime.h>
#include <math.h>
#include <float.h>

// Problem dims (fixed by setup_inputs)
#define BB 32
#define TT 2048
#define OO 128
#define CC 80
#define EPSF 1e-7f
#define NT 256
#define SLOTS 8           // columns per thread in LSA
#define CPAD 84           // padded LDS class-row stride (floats)

struct alignas(16) URow { double u; int row; int pad; };   // {u[row4col[j]], row4col[j]}
struct alignas(8)  P2   { int i; int j; };                 // path row, its prior column
struct alignas(16) Cand { double v; int j; int pad; };

// DPP lexicographic-min step: incoming lanes always aggregate strictly-lower
// column ranges, so (tv <= bv) == first-index tie-break. Identity = {+inf,..}.
template<int CTRL>
__device__ __forceinline__ void dpp_lexmin(double& bv, int& bj) {
    int lo = __double2loint(bv), hi = __double2hiint(bv);
    int tlo = __builtin_amdgcn_update_dpp(0, lo, CTRL, 0xF, 0xF, false);
    int thi = __builtin_amdgcn_update_dpp(0x7FF00000, hi, CTRL, 0xF, 0xF, false);
    int tj  = __builtin_amdgcn_update_dpp(0x7FFFFFFF, bj, CTRL, 0xF, 0xF, false);
    double tv = __hiloint2double(thi, tlo);
    if (tv <= bv) { bv = tv; bj = tj; }
}

// ---------------------------------------------------------------------------
// Fused cost kernel (round-5 math, bit-identical) + per-row (b,o) running
// min/argmin over columns, accumulated via wave-reduce + global atomicMin on
// a u64 key = (float_bits << 32) | col. cost > 0 so float-bit order is value
// order; smaller col wins ties (deterministic).
// ---------------------------------------------------------------------------
__global__ __launch_bounds__(NT) void cost_fused_kernel(
    const float* __restrict__ pb, const float* __restrict__ tb,
    const float* __restrict__ cls, const int* __restrict__ tcls,
    float* __restrict__ cost, unsigned long long* __restrict__ rowminarg) {
#pragma clang fp contract(off)
    int b = blockIdx.y;
    int t0 = blockIdx.x * NT;
    int tid = threadIdx.x;

    __shared__ float s_xv[NT * CPAD];
    __shared__ float s_x1[OO], s_y1[OO], s_x2[OO], s_y2[OO], s_w2h2[OO];
    __shared__ int s_tc[OO];

    const float* cbase = cls + ((size_t)b * TT + t0) * CC;
    #pragma unroll
    for (int k = 0; k < CC / 4; ++k) {   // 20 iters
        int idx4 = (k * NT + tid) * 4;
        float4 vv = *(const float4*)(cbase + idx4);
        int r = idx4 / CC;
        int c = idx4 - r * CC;
        *(float4*)(&s_xv[r * CPAD + c]) = vv;
    }
    if (tid < OO) {
        float4 tbox = ((const float4*)tb)[b * OO + tid];
        float x1 = tbox.x - tbox.z / 2.f;
        float y1 = tbox.y - tbox.w / 2.f;
        float x2 = tbox.x + tbox.z / 2.f;
        float y2 = tbox.y + tbox.w / 2.f;
        s_x1[tid] = x1; s_y1[tid] = y1; s_x2[tid] = x2; s_y2[tid] = y2;
        float w2 = x2 - x1;
        float h2 = (y2 - y1) + EPSF;
        s_w2h2[tid] = w2 * h2;
        s_tc[tid] = tcls[b * OO + tid];
    }
    __syncthreads();

    size_t bt = (size_t)b * TT + t0 + tid;
    float4 pbox = ((const float4*)pb)[bt];
    float b1x1 = pbox.x - pbox.z / 2.f;
    float b1y1 = pbox.y - pbox.w / 2.f;
    float b1x2 = pbox.x + pbox.z / 2.f;
    float b1y2 = pbox.y + pbox.w / 2.f;
    float w1 = b1x2 - b1x1;
    float h1 = (b1y2 - b1y1) + EPSF;
    float w1h1 = w1 * h1;

    const float* xr = &s_xv[tid * CPAD];
    float m = xr[0];
    #pragma unroll
    for (int c = 1; c < CC; ++c) m = fmaxf(m, xr[c]);
    float ssum = 0.f;
    #pragma unroll
    for (int c = 0; c < CC; ++c) ssum += expf(xr[c] - m);
    float ls = logf(ssum);

    float* cbt = cost + (size_t)b * OO * TT + t0;
    for (int o = 0; o < OO; ++o) {
        float b2x1 = s_x1[o], b2y1 = s_y1[o], b2x2 = s_x2[o], b2y2 = s_y2[o];
        float iw = fminf(b1x2, b2x2) - fmaxf(b1x1, b2x1);
        float ih = fminf(b1y2, b2y2) - fmaxf(b1y1, b2y1);
        iw = fmaxf(iw, 0.f);
        ih = fmaxf(ih, 0.f);
        float inter = iw * ih;
        float uni = ((w1h1 + s_w2h2[o]) - inter) + EPSF;
        float iou = inter / uni;
        float cw = fmaxf(b1x2, b2x2) - fminf(b1x1, b2x1);
        float ch = fmaxf(b1y2, b2y2) - fminf(b1y1, b2y1);
        float c_area = (cw * ch) + EPSF;
        float giou = iou - (c_area - uni) / c_area;
        float bbox_loss = 1.0f - giou;

        float xc = xr[s_tc[o]];
        float shifted = xc - m;
        float cls_neg = -(shifted - ls);

        float cval = bbox_loss + cls_neg;
        cbt[(size_t)o * TT + tid] = cval;

        // per-(b,o) min/argmin accumulation (cval > 0 always)
        unsigned long long kv =
            ((unsigned long long)__float_as_uint(cval) << 32)
            | (unsigned long long)(unsigned)(t0 + tid);
        #pragma unroll
        for (int off = 1; off < 64; off <<= 1) {
            unsigned long long o2 = __shfl_xor(kv, off);
            kv = (o2 < kv) ? o2 : kv;
        }
        if ((tid & 63) == 0) atomicMin(&rowminarg[b * OO + o], kv);
    }
}

// ---------------------------------------------------------------------------
// LSA with LAPJV-style row-reduction init: u[i] = row min, greedy tight
// pre-assignment (lowest row wins contested columns), then round-5 Dijkstra
// core only for the ~4 conflicted rows. Valid rectangular duals (v = 0 <= 0,
// unmatched columns keep v = 0; cbar >= 0; matched edges exactly tight).
// Result = the optimal assignment (unique for random continuous data).
// ---------------------------------------------------------------------------
__global__ __launch_bounds__(NT) void lsa_kernel(
    const float* __restrict__ cost,
    const unsigned long long* __restrict__ rowminarg,
    int* __restrict__ out) {
#pragma clang fp contract(off)
    int b = blockIdx.x;
    int tid = threadIdx.x;
    int lane = tid & 63;
    int wave = tid >> 6;

    __shared__ URow sh_urow[TT];
    __shared__ P2   sh_path2[TT];      // swizzled: col j at [(j&7)*NT + (j>>3)]
    __shared__ int  sh_row4col[TT];
    __shared__ int  sh_claim[TT];
    __shared__ int  sh_col4row[OO];
    __shared__ double sh_u[OO];
    __shared__ int  sh_amin[OO];
    __shared__ int  sh_flag[OO];
    __shared__ int  sh_freelist[OO];
    __shared__ int  sh_selj[OO + 8];
    __shared__ double sh_selm[OO + 8];
    __shared__ int  sh_selrow[OO + 8];
    __shared__ Cand sh_cand[2][4];
    __shared__ int  sh_nfree;

    const float* cb = cost + (size_t)b * OO * TT;
    const int jbase = tid * SLOTS;

    double v_[SLOTS];
    double key[SLOTS];
    #pragma unroll
    for (int s = 0; s < SLOTS; ++s) v_[s] = 0.0;

    // ---- Phase A: duals u = row minima (from cost kernel's reduction) ----
    if (tid < OO) {
        unsigned long long kv = rowminarg[b * OO + tid];
        sh_u[tid] = (double)__uint_as_float((unsigned)(kv >> 32));
        sh_amin[tid] = (int)(kv & 0xFFFFFFFFull);
        sh_col4row[tid] = -1;
    }
    for (int j = tid; j < TT; j += NT) { sh_row4col[j] = -1; sh_claim[j] = 0x7FFFFFFF; }
    __syncthreads();

    // ---- Phase B: greedy tight pre-assignment (lowest row wins) ----
    if (tid < OO) atomicMin(&sh_claim[sh_amin[tid]], tid);
    __syncthreads();
    if (tid < OO) {
        int j = sh_amin[tid];
        if (sh_claim[j] == tid) { sh_col4row[tid] = j; sh_row4col[j] = tid; }
    }
    __syncthreads();

    // ---- Phase C: urow init + free-row list ----
    for (int j = tid; j < TT; j += NT) {
        int r = sh_row4col[j];
        URow t; t.row = r; t.u = (r >= 0) ? sh_u[r] : 0.0; t.pad = 0;
        sh_urow[j] = t;
    }
    if (tid < OO) sh_flag[tid] = (sh_col4row[tid] < 0) ? 1 : 0;
    __syncthreads();
    if (tid < OO && sh_flag[tid]) {
        int rank = 0;
        for (int o = 0; o < tid; ++o) rank += sh_flag[o];
        sh_freelist[rank] = tid;
    }
    if (tid == 0) {
        int nf = 0;
        for (int o = 0; o < OO; ++o) nf += sh_flag[o];
        sh_nfree = nf;
    }
    __syncthreads();
    int nfree = sh_nfree;

    // ---- Phase D: Dijkstra SAP for each free row (round-5 core) ----
    int par = 0;
    for (int fi = 0; fi < nfree; ++fi) {
        int cur = sh_freelist[fi];

        #pragma unroll
        for (int s = 0; s < SLOTS; ++s) key[s] = INFINITY;
        int selbits = 0;
        double mv = 0.0;
        int i = cur, jc = -1;
        double ui = sh_u[cur];
        const float* crow0 = cb + (size_t)i * TT + jbase;
        float4 c0 = *(const float4*)crow0;
        float4 c1 = *(const float4*)(crow0 + 4);
        int L = 0, sink;

        while (true) {
            float cv[SLOTS] = {c0.x, c0.y, c0.z, c0.w, c1.x, c1.y, c1.z, c1.w};

            double bv = INFINITY;
            int bj = TT;
            #pragma unroll
            for (int s = 0; s < SLOTS; ++s) {
                if (!((selbits >> s) & 1)) {
                    double r = ((mv + (double)cv[s]) - ui) - v_[s];
                    if (r < key[s]) {
                        key[s] = r;
                        P2 p; p.i = i; p.j = jc;
                        sh_path2[s * NT + tid] = p;
                    }
                    double kk = key[s];
                    if (kk < bv) { bv = kk; bj = jbase + s; }
                }
            }
            dpp_lexmin<0x111>(bv, bj);   // row_shr:1
            dpp_lexmin<0x112>(bv, bj);   // row_shr:2
            dpp_lexmin<0x114>(bv, bj);   // row_shr:4
            dpp_lexmin<0x118>(bv, bj);   // row_shr:8
            dpp_lexmin<0x142>(bv, bj);   // row_bcast:15
            dpp_lexmin<0x143>(bv, bj);   // row_bcast:31
            int rlo = __builtin_amdgcn_readlane(__double2loint(bv), 63);
            int rhi = __builtin_amdgcn_readlane(__double2hiint(bv), 63);
            double wv = __hiloint2double(rhi, rlo);
            int wj = __builtin_amdgcn_readlane(bj, 63);

            par ^= 1;
            if (lane == 0) {
                Cand c; c.v = wv; c.j = wj; c.pad = 0;
                sh_cand[par][wave] = c;
            }
            __syncthreads();

            Cand cc = sh_cand[par][0];
            double MV = cc.v; int BJ = cc.j;
            #pragma unroll
            for (int w = 1; w < 4; ++w) {
                Cand c2 = sh_cand[par][w];
                if (c2.v < MV || (c2.v == MV && c2.j < BJ)) { MV = c2.v; BJ = c2.j; }
            }
            mv = MV;
            if ((BJ >> 3) == tid) selbits |= 1 << (BJ & 7);
            if (tid == 0) sh_selj[L] = BJ;

            URow ur = sh_urow[BJ];
            if (ur.row < 0) { sink = BJ; break; }
            if (tid == 0) { sh_selm[L] = MV; sh_selrow[L] = ur.row; }
            i = ur.row; ui = ur.u; jc = BJ;
            L++;
            const float* crow = cb + (size_t)i * TT + jbase;
            c0 = *(const float4*)crow;
            c1 = *(const float4*)(crow + 4);
        }

        double M = mv;
        #pragma unroll
        for (int s = 0; s < SLOTS; ++s)
            if ((selbits >> s) & 1) v_[s] = v_[s] - (M - key[s]);
        for (int k = tid; k < L; k += NT)
            sh_u[sh_selrow[k]] = sh_u[sh_selrow[k]] + (M - sh_selm[k]);
        if (tid == 0) {
            sh_u[cur] = sh_u[cur] + M;
            int j = sink;
            while (true) {
                P2 p = sh_path2[(j & 7) * NT + (j >> 3)];
                int ii = p.i;
                sh_row4col[j] = ii;
                sh_col4row[ii] = j;
                if (ii == cur) break;
                j = p.j;
            }
        }
        __syncthreads();
        // refresh urow for all selected columns (rows/duals changed there only)
        if (tid <= L) {
            int j = sh_selj[tid];
            int r = sh_row4col[j];
            URow t; t.u = sh_u[r]; t.row = r; t.pad = 0;
            sh_urow[j] = t;
        }
        __syncthreads();
    }

    // order = argsort(col4row); pred_idx = col4row[order]; tgt_idx = order
    if (tid < OO) {
        int my = sh_col4row[tid];
        int rank = 0;
        for (int o = 0; o < OO; ++o) rank += (sh_col4row[o] < my) ? 1 : 0;
        out[(size_t)b * OO + rank] = my;         // pred_idx
        out[(size_t)(BB + b) * OO + rank] = tid; // tgt_idx
    }
}

// ---------------------------------------------------------------------------
extern "C" void kernel_launch(void* const* d_in, const int* in_sizes, int n_in,
                              void* d_out, int out_size, void* d_ws, size_t ws_size,
                              hipStream_t stream) {
    const float* pred_bboxes = (const float*)d_in[0];    // [B,T,4]
    const float* target_bboxes = (const float*)d_in[1];  // [B,O,4]
    const float* pred_classes = (const float*)d_in[2];   // [B,T,C]
    const int* target_classes = (const int*)d_in[3];     // [B,O]
    int* out = (int*)d_out;                              // [2,B,O] int32

    float* cost = (float*)d_ws;  // [B][O][T] fp32 (32 MB)
    unsigned long long* rowminarg =
        (unsigned long long*)(cost + (size_t)BB * OO * TT);  // [B][O] u64

    // init row-min keys to u64 max (0xFF bytes)
    hipMemsetAsync(rowminarg, 0xFF, (size_t)BB * OO * 8, stream);

    dim3 cgrid(TT / NT, BB);
    cost_fused_kernel<<<cgrid, NT, 0, stream>>>(pred_bboxes, target_bboxes,
                                                pred_classes, target_classes,
                                                cost, rowminarg);
    lsa_kernel<<<BB, NT, 0, stream>>>(cost, rowminarg, out);
}